// Round 1
// baseline (1092.131 us; speedup 1.0000x reference)
//
#include <hip/hip_runtime.h>

// GraphSAGE 3-layer encoder, MI355X.
// Strategy: transform-then-aggregate (mean agg is linear), CSR built per-launch.

// ---------------- CSR build ----------------

__global__ void count_deg_k(const int* __restrict__ dst, int* __restrict__ deg, int E) {
    int e = blockIdx.x * blockDim.x + threadIdx.x;
    if (e < E) atomicAdd(&deg[dst[e]], 1);
}

// Exclusive scan, phase 1: blocks of 1024 elems (256 thr x 4), per-block exclusive + block sums.
__global__ void scan_blocks_k(const int* __restrict__ deg, int* __restrict__ rp,
                              int* __restrict__ partials, int n) {
    __shared__ int s[256];
    int t = threadIdx.x;
    int base = blockIdx.x * 1024;
    int v[4];
    int sum = 0;
#pragma unroll
    for (int k = 0; k < 4; k++) {
        int idx = base + t * 4 + k;
        v[k] = (idx < n) ? deg[idx] : 0;
        sum += v[k];
    }
    s[t] = sum;
    __syncthreads();
    for (int off = 1; off < 256; off <<= 1) {
        int x = (t >= off) ? s[t - off] : 0;
        __syncthreads();
        s[t] += x;
        __syncthreads();
    }
    if (t == 255) partials[blockIdx.x] = s[255];
    int run = s[t] - sum;  // exclusive within block
#pragma unroll
    for (int k = 0; k < 4; k++) {
        int idx = base + t * 4 + k;
        if (idx < n) rp[idx] = run;
        run += v[k];
    }
}

// Phase 2: scan the (<=256) block sums in one block, in-place exclusive.
__global__ void scan_partials_k(int* __restrict__ p, int nb) {
    __shared__ int s[256];
    int t = threadIdx.x;
    int v = (t < nb) ? p[t] : 0;
    s[t] = v;
    __syncthreads();
    for (int off = 1; off < 256; off <<= 1) {
        int x = (t >= off) ? s[t - off] : 0;
        __syncthreads();
        s[t] += x;
        __syncthreads();
    }
    if (t < nb) p[t] = s[t] - v;
}

// Phase 3: add block offsets; init cursor = rowptr; set rp[n] = E.
__global__ void finalize_rp_k(int* __restrict__ rp, const int* __restrict__ partials,
                              int* __restrict__ cursor, int n, int E) {
    int i = blockIdx.x * blockDim.x + threadIdx.x;
    if (i < n) {
        int v = rp[i] + partials[i >> 10];
        rp[i] = v;
        cursor[i] = v;
    }
    if (i == 0) rp[n] = E;
}

__global__ void fill_adj_k(const int* __restrict__ src, const int* __restrict__ dst,
                           int* __restrict__ cursor, int* __restrict__ adj, int E) {
    int e = blockIdx.x * blockDim.x + threadIdx.x;
    if (e < E) {
        int pos = atomicAdd(&cursor[dst[e]], 1);
        adj[pos] = src[e];
    }
}

// ---------------- dual GEMM: Y = H @ Wl^T ; Z = H @ Wr^T + b ----------------
// din fixed = 64. Block handles 16 rows. Weights staged transposed in LDS.

template <int DOUT>
__global__ __launch_bounds__(256) void gemm_dual_k(const float* __restrict__ H,
                                                   const float* __restrict__ Wl,
                                                   const float* __restrict__ Wr,
                                                   const float* __restrict__ b,
                                                   float* __restrict__ Y,
                                                   float* __restrict__ Z, int N) {
    constexpr int DOUT2 = 2 * DOUT;
    constexpr int ST = DOUT2 + 1;          // padded LDS stride (bank-conflict-free)
    constexpr int RT = 16 * DOUT2 / 256;   // rows per thread
    __shared__ float wT[64 * (2 * 64 + 1)];
    int t = threadIdx.x;
    // stage combined [Wl; Wr] transposed: wT[j][c]
    for (int idx = t; idx < DOUT2 * 64; idx += 256) {
        int c = idx >> 6, j = idx & 63;
        float w = (c < DOUT) ? Wl[c * 64 + j] : Wr[(c - DOUT) * 64 + j];
        wT[j * ST + c] = w;
    }
    __syncthreads();

    int c2 = t % DOUT2;
    int rg = t / DOUT2;
    int rb = blockIdx.x * 16 + rg * RT;
    const float4* H4 = reinterpret_cast<const float4*>(H);

    int rbase[RT];
#pragma unroll
    for (int r = 0; r < RT; r++) {
        int row = rb + r;
        rbase[r] = ((row < N) ? row : (N - 1)) * 16;
    }
    float acc[RT];
#pragma unroll
    for (int r = 0; r < RT; r++) acc[r] = 0.f;

#pragma unroll
    for (int j4 = 0; j4 < 16; j4++) {
        float w0 = wT[(4 * j4 + 0) * ST + c2];
        float w1 = wT[(4 * j4 + 1) * ST + c2];
        float w2 = wT[(4 * j4 + 2) * ST + c2];
        float w3 = wT[(4 * j4 + 3) * ST + c2];
#pragma unroll
        for (int r = 0; r < RT; r++) {
            float4 h = H4[rbase[r] + j4];  // wave-uniform broadcast load
            acc[r] = fmaf(h.x, w0, fmaf(h.y, w1, fmaf(h.z, w2, fmaf(h.w, w3, acc[r]))));
        }
    }
    float bias = (c2 >= DOUT) ? b[c2 - DOUT] : 0.f;
#pragma unroll
    for (int r = 0; r < RT; r++) {
        int row = rb + r;
        if (row < N) {
            if (c2 < DOUT)
                Y[row * DOUT + c2] = acc[r];
            else
                Z[row * DOUT + (c2 - DOUT)] = acc[r] + bias;
        }
    }
}

// ---------------- aggregate: H[i] += mean_{e in adj(i)} Y[adj[e]] ; opt ReLU ----------------
// One wave per (64/DOUT) nodes; lane -> feature dim. Gathers are contiguous DOUT*4B rows.

template <int DOUT, bool RELU>
__global__ __launch_bounds__(256) void aggregate_k(const int* __restrict__ rp,
                                                   const int* __restrict__ adj,
                                                   const float* __restrict__ Y,
                                                   float* __restrict__ H, int N) {
    constexpr int NPW = 64 / DOUT;
    int wave = threadIdx.x >> 6;
    int lane = threadIdx.x & 63;
    int sub = lane / DOUT;
    int d = lane % DOUT;
    int node = (blockIdx.x * 4 + wave) * NPW + sub;
    if (node >= N) return;
    int s0 = rp[node], s1 = rp[node + 1];
    float acc = 0.f;
    int e = s0;
    for (; e + 4 <= s1; e += 4) {
        int a0 = adj[e], a1 = adj[e + 1], a2 = adj[e + 2], a3 = adj[e + 3];
        float y0 = Y[a0 * DOUT + d];
        float y1 = Y[a1 * DOUT + d];
        float y2 = Y[a2 * DOUT + d];
        float y3 = Y[a3 * DOUT + d];
        acc += y0;
        acc += y1;
        acc += y2;
        acc += y3;
    }
    for (; e < s1; e++) acc += Y[adj[e] * DOUT + d];
    int deg = s1 - s0;
    float v = H[node * DOUT + d];
    if (deg > 0) v += acc / (float)deg;
    if (RELU) v = fmaxf(v, 0.f);
    H[node * DOUT + d] = v;
}

// ---------------- launch ----------------

extern "C" void kernel_launch(void* const* d_in, const int* in_sizes, int n_in,
                              void* d_out, int out_size, void* d_ws, size_t ws_size,
                              hipStream_t stream) {
    const float* x = (const float*)d_in[0];
    const int* ei = (const int*)d_in[1];  // int32 (JAX x64-disabled downcast)
    // d_in[2] edge_weight ignored per reference
    const float* Wl0 = (const float*)d_in[3];
    const float* Wr0 = (const float*)d_in[4];
    const float* b0 = (const float*)d_in[5];
    const float* Wl1 = (const float*)d_in[6];
    const float* Wr1 = (const float*)d_in[7];
    const float* b1 = (const float*)d_in[8];
    const float* Wl2 = (const float*)d_in[9];
    const float* Wr2 = (const float*)d_in[10];
    const float* b2 = (const float*)d_in[11];

    int N = in_sizes[0] / 64;
    int E = in_sizes[1] / 2;
    const int* src = ei;
    const int* dstp = ei + E;

    char* ws = (char*)d_ws;
    size_t off = 0;
    auto take = [&](size_t bytes) -> void* {
        void* p = ws + off;
        off = (off + bytes + 255) & ~(size_t)255;
        return p;
    };
    int* rowptr = (int*)take((size_t)(N + 1) * 4);
    int* cursor = (int*)take((size_t)N * 4);
    int* partials = (int*)take(4096);
    int* adj = (int*)take((size_t)E * 4);
    float* Y = (float*)take((size_t)N * 64 * 4);
    float* HA = (float*)take((size_t)N * 64 * 4);
    float* HB = (float*)take((size_t)N * 64 * 4);
    (void)ws_size;
    (void)n_in;
    (void)out_size;

    // CSR build
    hipMemsetAsync(cursor, 0, (size_t)N * 4, stream);
    count_deg_k<<<(E + 255) / 256, 256, 0, stream>>>(dstp, cursor, E);
    int nb = (N + 1023) / 1024;
    scan_blocks_k<<<nb, 256, 0, stream>>>(cursor, rowptr, partials, N);
    scan_partials_k<<<1, 256, 0, stream>>>(partials, nb);
    finalize_rp_k<<<(N + 255) / 256, 256, 0, stream>>>(rowptr, partials, cursor, N, E);
    fill_adj_k<<<(E + 255) / 256, 256, 0, stream>>>(src, dstp, cursor, adj, E);

    float* out = (float*)d_out;

    // layer 0: x -> HA (relu)
    gemm_dual_k<64><<<(N + 15) / 16, 256, 0, stream>>>(x, Wl0, Wr0, b0, Y, HA, N);
    aggregate_k<64, true><<<(N + 3) / 4, 256, 0, stream>>>(rowptr, adj, Y, HA, N);
    // layer 1: HA -> HB (relu)
    gemm_dual_k<64><<<(N + 15) / 16, 256, 0, stream>>>(HA, Wl1, Wr1, b1, Y, HB, N);
    aggregate_k<64, true><<<(N + 3) / 4, 256, 0, stream>>>(rowptr, adj, Y, HB, N);
    // layer 2: HB -> out (no relu)
    gemm_dual_k<32><<<(N + 15) / 16, 256, 0, stream>>>(HB, Wl2, Wr2, b2, Y, out, N);
    aggregate_k<32, false><<<(N + 7) / 8, 256, 0, stream>>>(rowptr, adj, Y, out, N);
}

// Round 2
// 669.552 us; speedup vs baseline: 1.6311x; 1.6311x over previous
//
#include <hip/hip_runtime.h>

// GraphSAGE 3-layer encoder, MI355X.
// Strategy: transform-then-aggregate (mean agg is linear), CSR built per-launch.
// R1 fix: gemm_dual_k spilled (VGPR=256, 563MB scratch writes) -> RT=4,
// bounded unroll, __launch_bounds__(256,4). Everything else unchanged.

// ---------------- CSR build ----------------

__global__ void count_deg_k(const int* __restrict__ dst, int* __restrict__ deg, int E) {
    int e = blockIdx.x * blockDim.x + threadIdx.x;
    if (e < E) atomicAdd(&deg[dst[e]], 1);
}

// Exclusive scan, phase 1: blocks of 1024 elems (256 thr x 4), per-block exclusive + block sums.
__global__ void scan_blocks_k(const int* __restrict__ deg, int* __restrict__ rp,
                              int* __restrict__ partials, int n) {
    __shared__ int s[256];
    int t = threadIdx.x;
    int base = blockIdx.x * 1024;
    int v[4];
    int sum = 0;
#pragma unroll
    for (int k = 0; k < 4; k++) {
        int idx = base + t * 4 + k;
        v[k] = (idx < n) ? deg[idx] : 0;
        sum += v[k];
    }
    s[t] = sum;
    __syncthreads();
    for (int off = 1; off < 256; off <<= 1) {
        int x = (t >= off) ? s[t - off] : 0;
        __syncthreads();
        s[t] += x;
        __syncthreads();
    }
    if (t == 255) partials[blockIdx.x] = s[255];
    int run = s[t] - sum;  // exclusive within block
#pragma unroll
    for (int k = 0; k < 4; k++) {
        int idx = base + t * 4 + k;
        if (idx < n) rp[idx] = run;
        run += v[k];
    }
}

// Phase 2: scan the (<=256) block sums in one block, in-place exclusive.
__global__ void scan_partials_k(int* __restrict__ p, int nb) {
    __shared__ int s[256];
    int t = threadIdx.x;
    int v = (t < nb) ? p[t] : 0;
    s[t] = v;
    __syncthreads();
    for (int off = 1; off < 256; off <<= 1) {
        int x = (t >= off) ? s[t - off] : 0;
        __syncthreads();
        s[t] += x;
        __syncthreads();
    }
    if (t < nb) p[t] = s[t] - v;
}

// Phase 3: add block offsets; init cursor = rowptr; set rp[n] = E.
__global__ void finalize_rp_k(int* __restrict__ rp, const int* __restrict__ partials,
                              int* __restrict__ cursor, int n, int E) {
    int i = blockIdx.x * blockDim.x + threadIdx.x;
    if (i < n) {
        int v = rp[i] + partials[i >> 10];
        rp[i] = v;
        cursor[i] = v;
    }
    if (i == 0) rp[n] = E;
}

__global__ void fill_adj_k(const int* __restrict__ src, const int* __restrict__ dst,
                           int* __restrict__ cursor, int* __restrict__ adj, int E) {
    int e = blockIdx.x * blockDim.x + threadIdx.x;
    if (e < E) {
        int pos = atomicAdd(&cursor[dst[e]], 1);
        adj[pos] = src[e];
    }
}

// ---------------- dual GEMM: Y = H @ Wl^T ; Z = H @ Wr^T + b ----------------
// din fixed = 64. Weights staged transposed in LDS. lane -> output col,
// RT=4 rows/thread, bounded unroll so in-flight float4 loads stay <= 64 VGPRs.

template <int DOUT>
__global__ __launch_bounds__(256, 4) void gemm_dual_k(const float* __restrict__ H,
                                                      const float* __restrict__ Wl,
                                                      const float* __restrict__ Wr,
                                                      const float* __restrict__ b,
                                                      float* __restrict__ Y,
                                                      float* __restrict__ Z, int N) {
    constexpr int DOUT2 = 2 * DOUT;       // 128 (d=64) or 64 (d=32)
    constexpr int ST = DOUT2 + 1;         // padded LDS stride
    __shared__ float wT[64 * ST];         // [input j][output c]
    int t = threadIdx.x;
    for (int idx = t; idx < DOUT2 * 64; idx += 256) {
        int c = idx >> 6, j = idx & 63;
        float w = (c < DOUT) ? Wl[c * 64 + j] : Wr[(c - DOUT) * 64 + j];
        wT[j * ST + c] = w;
    }
    __syncthreads();

    constexpr int RG = 256 / DOUT2;       // row-groups per block: 2 or 4
    constexpr int RT = 4;                 // rows per thread
    constexpr int ROWS = RG * RT;         // rows per block: 8 or 16

    int c2 = t % DOUT2;
    int rg = t / DOUT2;
    int row0 = blockIdx.x * ROWS + rg * RT;

    const float4* H4 = reinterpret_cast<const float4*>(H);

    int rbase[RT];
#pragma unroll
    for (int r = 0; r < RT; r++) {
        int row = row0 + r;
        rbase[r] = ((row < N) ? row : 0) * 16;
    }
    float acc[RT];
#pragma unroll
    for (int r = 0; r < RT; r++) acc[r] = 0.f;

#pragma unroll 4
    for (int j4 = 0; j4 < 16; j4++) {
        float4 h[RT];
#pragma unroll
        for (int r = 0; r < RT; r++) h[r] = H4[rbase[r] + j4];  // wave-uniform broadcast
        float w0 = wT[(4 * j4 + 0) * ST + c2];
        float w1 = wT[(4 * j4 + 1) * ST + c2];
        float w2 = wT[(4 * j4 + 2) * ST + c2];
        float w3 = wT[(4 * j4 + 3) * ST + c2];
#pragma unroll
        for (int r = 0; r < RT; r++) {
            acc[r] = fmaf(h[r].x, w0,
                     fmaf(h[r].y, w1, fmaf(h[r].z, w2, fmaf(h[r].w, w3, acc[r]))));
        }
    }
    float bias = (c2 >= DOUT) ? b[c2 - DOUT] : 0.f;
#pragma unroll
    for (int r = 0; r < RT; r++) {
        int row = row0 + r;
        if (row < N) {
            if (c2 < DOUT)
                Y[row * DOUT + c2] = acc[r];
            else
                Z[row * DOUT + (c2 - DOUT)] = acc[r] + bias;
        }
    }
}

// ---------------- aggregate: H[i] += mean_{e in adj(i)} Y[adj[e]] ; opt ReLU ----------------
// One wave per (64/DOUT) nodes; lane -> feature dim. Gathers are contiguous DOUT*4B rows.

template <int DOUT, bool RELU>
__global__ __launch_bounds__(256) void aggregate_k(const int* __restrict__ rp,
                                                   const int* __restrict__ adj,
                                                   const float* __restrict__ Y,
                                                   float* __restrict__ H, int N) {
    constexpr int NPW = 64 / DOUT;
    int wave = threadIdx.x >> 6;
    int lane = threadIdx.x & 63;
    int sub = lane / DOUT;
    int d = lane % DOUT;
    int node = (blockIdx.x * 4 + wave) * NPW + sub;
    if (node >= N) return;
    int s0 = rp[node], s1 = rp[node + 1];
    float acc = 0.f;
    int e = s0;
    for (; e + 4 <= s1; e += 4) {
        int a0 = adj[e], a1 = adj[e + 1], a2 = adj[e + 2], a3 = adj[e + 3];
        float y0 = Y[a0 * DOUT + d];
        float y1 = Y[a1 * DOUT + d];
        float y2 = Y[a2 * DOUT + d];
        float y3 = Y[a3 * DOUT + d];
        acc += y0;
        acc += y1;
        acc += y2;
        acc += y3;
    }
    for (; e < s1; e++) acc += Y[adj[e] * DOUT + d];
    int deg = s1 - s0;
    float v = H[node * DOUT + d];
    if (deg > 0) v += acc / (float)deg;
    if (RELU) v = fmaxf(v, 0.f);
    H[node * DOUT + d] = v;
}

// ---------------- launch ----------------

extern "C" void kernel_launch(void* const* d_in, const int* in_sizes, int n_in,
                              void* d_out, int out_size, void* d_ws, size_t ws_size,
                              hipStream_t stream) {
    const float* x = (const float*)d_in[0];
    const int* ei = (const int*)d_in[1];  // int32 (JAX x64-disabled downcast)
    // d_in[2] edge_weight ignored per reference
    const float* Wl0 = (const float*)d_in[3];
    const float* Wr0 = (const float*)d_in[4];
    const float* b0 = (const float*)d_in[5];
    const float* Wl1 = (const float*)d_in[6];
    const float* Wr1 = (const float*)d_in[7];
    const float* b1 = (const float*)d_in[8];
    const float* Wl2 = (const float*)d_in[9];
    const float* Wr2 = (const float*)d_in[10];
    const float* b2 = (const float*)d_in[11];

    int N = in_sizes[0] / 64;
    int E = in_sizes[1] / 2;
    const int* src = ei;
    const int* dstp = ei + E;

    char* ws = (char*)d_ws;
    size_t off = 0;
    auto take = [&](size_t bytes) -> void* {
        void* p = ws + off;
        off = (off + bytes + 255) & ~(size_t)255;
        return p;
    };
    int* rowptr = (int*)take((size_t)(N + 1) * 4);
    int* cursor = (int*)take((size_t)N * 4);
    int* partials = (int*)take(4096);
    int* adj = (int*)take((size_t)E * 4);
    float* Y = (float*)take((size_t)N * 64 * 4);
    float* HA = (float*)take((size_t)N * 64 * 4);
    float* HB = (float*)take((size_t)N * 64 * 4);
    (void)ws_size;
    (void)n_in;
    (void)out_size;

    // CSR build
    hipMemsetAsync(cursor, 0, (size_t)N * 4, stream);
    count_deg_k<<<(E + 255) / 256, 256, 0, stream>>>(dstp, cursor, E);
    int nb = (N + 1023) / 1024;
    scan_blocks_k<<<nb, 256, 0, stream>>>(cursor, rowptr, partials, N);
    scan_partials_k<<<1, 256, 0, stream>>>(partials, nb);
    finalize_rp_k<<<(N + 255) / 256, 256, 0, stream>>>(rowptr, partials, cursor, N, E);
    fill_adj_k<<<(E + 255) / 256, 256, 0, stream>>>(src, dstp, cursor, adj, E);

    float* out = (float*)d_out;

    // layer 0: x -> HA (relu)
    gemm_dual_k<64><<<(N + 7) / 8, 256, 0, stream>>>(x, Wl0, Wr0, b0, Y, HA, N);
    aggregate_k<64, true><<<(N + 3) / 4, 256, 0, stream>>>(rowptr, adj, Y, HA, N);
    // layer 1: HA -> HB (relu)
    gemm_dual_k<64><<<(N + 7) / 8, 256, 0, stream>>>(HA, Wl1, Wr1, b1, Y, HB, N);
    aggregate_k<64, true><<<(N + 3) / 4, 256, 0, stream>>>(rowptr, adj, Y, HB, N);
    // layer 2: HB -> out (no relu)
    gemm_dual_k<32><<<(N + 15) / 16, 256, 0, stream>>>(HB, Wl2, Wr2, b2, Y, out, N);
    aggregate_k<32, false><<<(N + 7) / 8, 256, 0, stream>>>(rowptr, adj, Y, out, N);
}

// Round 3
// 442.630 us; speedup vs baseline: 2.4674x; 1.5127x over previous
//
#include <hip/hip_runtime.h>

// GraphSAGE 3-layer encoder, MI355X.
// Transform-then-aggregate (mean agg is linear), CSR built per-launch.
// R2: register-blocked tiled GEMM (64-row tile in LDS, 4x8 register tile per
// thread, 10:1 FMA:LDS ratio); float4-lane aggregate with edge slots.

// ---------------- CSR build ----------------

__global__ void count_deg_k(const int* __restrict__ dst, int* __restrict__ deg, int E) {
    int e = blockIdx.x * blockDim.x + threadIdx.x;
    if (e < E) atomicAdd(&deg[dst[e]], 1);
}

__global__ void scan_blocks_k(const int* __restrict__ deg, int* __restrict__ rp,
                              int* __restrict__ partials, int n) {
    __shared__ int s[256];
    int t = threadIdx.x;
    int base = blockIdx.x * 1024;
    int v[4];
    int sum = 0;
#pragma unroll
    for (int k = 0; k < 4; k++) {
        int idx = base + t * 4 + k;
        v[k] = (idx < n) ? deg[idx] : 0;
        sum += v[k];
    }
    s[t] = sum;
    __syncthreads();
    for (int off = 1; off < 256; off <<= 1) {
        int x = (t >= off) ? s[t - off] : 0;
        __syncthreads();
        s[t] += x;
        __syncthreads();
    }
    if (t == 255) partials[blockIdx.x] = s[255];
    int run = s[t] - sum;
#pragma unroll
    for (int k = 0; k < 4; k++) {
        int idx = base + t * 4 + k;
        if (idx < n) rp[idx] = run;
        run += v[k];
    }
}

__global__ void scan_partials_k(int* __restrict__ p, int nb) {
    __shared__ int s[256];
    int t = threadIdx.x;
    int v = (t < nb) ? p[t] : 0;
    s[t] = v;
    __syncthreads();
    for (int off = 1; off < 256; off <<= 1) {
        int x = (t >= off) ? s[t - off] : 0;
        __syncthreads();
        s[t] += x;
        __syncthreads();
    }
    if (t < nb) p[t] = s[t] - v;
}

__global__ void finalize_rp_k(int* __restrict__ rp, const int* __restrict__ partials,
                              int* __restrict__ cursor, int n, int E) {
    int i = blockIdx.x * blockDim.x + threadIdx.x;
    if (i < n) {
        int v = rp[i] + partials[i >> 10];
        rp[i] = v;
        cursor[i] = v;
    }
    if (i == 0) rp[n] = E;
}

__global__ void fill_adj_k(const int* __restrict__ src, const int* __restrict__ dst,
                           int* __restrict__ cursor, int* __restrict__ adj, int E) {
    int e = blockIdx.x * blockDim.x + threadIdx.x;
    if (e < E) {
        int pos = atomicAdd(&cursor[dst[e]], 1);
        adj[pos] = src[e];
    }
}

// ---------------- tiled dual GEMM: Y = H @ Wl^T ; Z = H @ Wr^T + b ----------------
// din = 64. Block: 64 rows x DOUT2 cols. Thread: 4 rows x (DOUT2/16) cols.
// LDS strides padded to 68 floats; cols interleaved (tx + 16*c) -> <=2-way conflicts.

template <int DOUT>
__global__ __launch_bounds__(256, 2) void gemm_tile_k(const float* __restrict__ H,
                                                      const float* __restrict__ Wl,
                                                      const float* __restrict__ Wr,
                                                      const float* __restrict__ b,
                                                      float* __restrict__ Y,
                                                      float* __restrict__ Z, int N) {
    constexpr int DOUT2 = 2 * DOUT;   // 128 or 64
    constexpr int CPT = DOUT2 / 16;   // cols/thread: 8 or 4
    constexpr int ST = 68;            // padded LDS stride (floats)
    __shared__ float hs[64 * ST];
    __shared__ float ws[DOUT2 * ST];
    int t = threadIdx.x;

    // stage combined weights [Wl; Wr] as ws[c][j]
    for (int i = t; i < DOUT2 * 16; i += 256) {
        int c = i >> 4, j4 = i & 15;
        float4 w = (c < DOUT) ? reinterpret_cast<const float4*>(Wl)[c * 16 + j4]
                              : reinterpret_cast<const float4*>(Wr)[(c - DOUT) * 16 + j4];
        *reinterpret_cast<float4*>(&ws[c * ST + j4 * 4]) = w;
    }
    // stage H tile (contiguous 16KB chunk, fully coalesced)
    {
        const float4* H4 = reinterpret_cast<const float4*>(H);
        long base4 = (long)blockIdx.x * 64 * 16;
        long max4 = (long)N * 16 - 1;
        for (int i = t; i < 64 * 16; i += 256) {
            long g = base4 + i;
            if (g > max4) g = max4;
            float4 h = H4[g];
            int row = i >> 4, j4 = i & 15;
            *reinterpret_cast<float4*>(&hs[row * ST + j4 * 4]) = h;
        }
    }
    __syncthreads();

    int tx = t & 15;   // col group: cols tx + 16*c
    int ty = t >> 4;   // row group: rows ty*4 .. ty*4+3
    float acc[4][CPT];
#pragma unroll
    for (int r = 0; r < 4; r++)
#pragma unroll
        for (int c = 0; c < CPT; c++) acc[r][c] = 0.f;

#pragma unroll 2
    for (int k4 = 0; k4 < 16; ++k4) {
        float4 a[4], w[CPT];
#pragma unroll
        for (int r = 0; r < 4; r++)
            a[r] = *reinterpret_cast<const float4*>(&hs[(ty * 4 + r) * ST + k4 * 4]);
#pragma unroll
        for (int c = 0; c < CPT; c++)
            w[c] = *reinterpret_cast<const float4*>(&ws[(tx + 16 * c) * ST + k4 * 4]);
#pragma unroll
        for (int r = 0; r < 4; r++)
#pragma unroll
            for (int c = 0; c < CPT; c++)
                acc[r][c] = fmaf(a[r].x, w[c].x,
                            fmaf(a[r].y, w[c].y,
                            fmaf(a[r].z, w[c].z, fmaf(a[r].w, w[c].w, acc[r][c]))));
    }

    int row0 = blockIdx.x * 64 + ty * 4;
#pragma unroll
    for (int r = 0; r < 4; r++) {
        int row = row0 + r;
        if (row >= N) break;
#pragma unroll
        for (int c = 0; c < CPT; c++) {
            int col = tx + 16 * c;
            if (col < DOUT)
                Y[row * DOUT + col] = acc[r][c];
            else
                Z[row * DOUT + (col - DOUT)] = acc[r][c] + b[col - DOUT];
        }
    }
}

// ---------------- aggregate: H[i] += mean_{e in adj(i)} Y[adj[e]] ; opt ReLU ----------------
// One wave per node. Row read as float4: FPR lanes per row, NSLOT edge slots.

template <int DOUT, bool RELU>
__global__ __launch_bounds__(256) void aggregate_k(const int* __restrict__ rp,
                                                   const int* __restrict__ adj,
                                                   const float* __restrict__ Y,
                                                   float* __restrict__ H, int N) {
    constexpr int FPR = DOUT / 4;        // float4 lanes per row: 16 or 8
    constexpr int NSLOT = 64 / FPR;      // edge slots: 4 or 8
    int wave = threadIdx.x >> 6;
    int lane = threadIdx.x & 63;
    int slot = lane / FPR;
    int d4 = lane % FPR;
    int node = blockIdx.x * 4 + wave;
    if (node >= N) return;
    int s0 = rp[node], s1 = rp[node + 1];
    const float4* Y4 = reinterpret_cast<const float4*>(Y);
    float4 acc = make_float4(0.f, 0.f, 0.f, 0.f);
    int e = s0 + slot;
    for (; e + NSLOT < s1; e += 2 * NSLOT) {
        int a0 = adj[e], a1 = adj[e + NSLOT];
        float4 y0 = Y4[(long)a0 * FPR + d4];
        float4 y1 = Y4[(long)a1 * FPR + d4];
        acc.x += y0.x; acc.y += y0.y; acc.z += y0.z; acc.w += y0.w;
        acc.x += y1.x; acc.y += y1.y; acc.z += y1.z; acc.w += y1.w;
    }
    if (e < s1) {
        float4 y0 = Y4[(long)adj[e] * FPR + d4];
        acc.x += y0.x; acc.y += y0.y; acc.z += y0.z; acc.w += y0.w;
    }
    // cross-slot reduce: lanes differing in slot bits (>= FPR)
#pragma unroll
    for (int m = FPR; m < 64; m <<= 1) {
        acc.x += __shfl_xor(acc.x, m);
        acc.y += __shfl_xor(acc.y, m);
        acc.z += __shfl_xor(acc.z, m);
        acc.w += __shfl_xor(acc.w, m);
    }
    int deg = s1 - s0;
    if (lane < FPR) {
        float4* H4 = reinterpret_cast<float4*>(H);
        float4 v = H4[(long)node * FPR + d4];
        if (deg > 0) {
            float inv = 1.f / (float)deg;
            v.x += acc.x * inv; v.y += acc.y * inv;
            v.z += acc.z * inv; v.w += acc.w * inv;
        }
        if (RELU) {
            v.x = fmaxf(v.x, 0.f); v.y = fmaxf(v.y, 0.f);
            v.z = fmaxf(v.z, 0.f); v.w = fmaxf(v.w, 0.f);
        }
        H4[(long)node * FPR + d4] = v;
    }
}

// ---------------- launch ----------------

extern "C" void kernel_launch(void* const* d_in, const int* in_sizes, int n_in,
                              void* d_out, int out_size, void* d_ws, size_t ws_size,
                              hipStream_t stream) {
    const float* x = (const float*)d_in[0];
    const int* ei = (const int*)d_in[1];  // int32
    const float* Wl0 = (const float*)d_in[3];
    const float* Wr0 = (const float*)d_in[4];
    const float* b0 = (const float*)d_in[5];
    const float* Wl1 = (const float*)d_in[6];
    const float* Wr1 = (const float*)d_in[7];
    const float* b1 = (const float*)d_in[8];
    const float* Wl2 = (const float*)d_in[9];
    const float* Wr2 = (const float*)d_in[10];
    const float* b2 = (const float*)d_in[11];

    int N = in_sizes[0] / 64;
    int E = in_sizes[1] / 2;
    const int* src = ei;
    const int* dstp = ei + E;

    char* ws = (char*)d_ws;
    size_t off = 0;
    auto take = [&](size_t bytes) -> void* {
        void* p = ws + off;
        off = (off + bytes + 255) & ~(size_t)255;
        return p;
    };
    int* rowptr = (int*)take((size_t)(N + 1) * 4);
    int* cursor = (int*)take((size_t)N * 4);
    int* partials = (int*)take(4096);
    int* adj = (int*)take((size_t)E * 4);
    float* Y = (float*)take((size_t)N * 64 * 4);
    float* HA = (float*)take((size_t)N * 64 * 4);
    float* HB = (float*)take((size_t)N * 64 * 4);
    (void)ws_size;
    (void)n_in;
    (void)out_size;

    // CSR build
    hipMemsetAsync(cursor, 0, (size_t)N * 4, stream);
    count_deg_k<<<(E + 255) / 256, 256, 0, stream>>>(dstp, cursor, E);
    int nb = (N + 1023) / 1024;
    scan_blocks_k<<<nb, 256, 0, stream>>>(cursor, rowptr, partials, N);
    scan_partials_k<<<1, 256, 0, stream>>>(partials, nb);
    finalize_rp_k<<<(N + 255) / 256, 256, 0, stream>>>(rowptr, partials, cursor, N, E);
    fill_adj_k<<<(E + 255) / 256, 256, 0, stream>>>(src, dstp, cursor, adj, E);

    float* out = (float*)d_out;
    int gb = (N + 63) / 64;
    int ab = (N + 3) / 4;

    // layer 0: x -> HA (relu)
    gemm_tile_k<64><<<gb, 256, 0, stream>>>(x, Wl0, Wr0, b0, Y, HA, N);
    aggregate_k<64, true><<<ab, 256, 0, stream>>>(rowptr, adj, Y, HA, N);
    // layer 1: HA -> HB (relu)
    gemm_tile_k<64><<<gb, 256, 0, stream>>>(HA, Wl1, Wr1, b1, Y, HB, N);
    aggregate_k<64, true><<<ab, 256, 0, stream>>>(rowptr, adj, Y, HB, N);
    // layer 2: HB -> out (no relu)
    gemm_tile_k<32><<<gb, 256, 0, stream>>>(HB, Wl2, Wr2, b2, Y, out, N);
    aggregate_k<32, false><<<ab, 256, 0, stream>>>(rowptr, adj, Y, out, N);
}